// Round 1
// 595.706 us; speedup vs baseline: 1.0118x; 1.0118x over previous
//
#include <hip/hip_runtime.h>
#include <hip/hip_bf16.h>

// EncoderLayer: B=4,S=2048,D=1024,H=16,DH=64,DFF=4096
// prep -> GEMM0 qkv (Q pre-scaled by log2e/sqrt(S)) -> k_trv -> mask bits -> remap
//   -> flash-attn (S^T, no-max softmax, QBLK=128: 32 q-rows/wave halves per-q LDS traffic)
//   -> GEMM1 -> GEMM2 -> GEMM3

#define SDIM 2048
#define DDIM 1024

using floatx4 = __attribute__((ext_vector_type(4))) float;
using bf16x8  = __attribute__((ext_vector_type(8))) __bf16;
using bf16x4  = __attribute__((ext_vector_type(4))) __bf16;
using short4v = __attribute__((ext_vector_type(4))) short;

#define GLDS16(gptr, lptr)                                                        \
    __builtin_amdgcn_global_load_lds(                                             \
        (const __attribute__((address_space(1))) void*)(uintptr_t)(gptr),         \
        (__attribute__((address_space(3))) void*)(uintptr_t)(lptr), 16, 0, 0)

// ---------------- prep kernels ----------------

__global__ void k_f2b(const float* __restrict__ in, __bf16* __restrict__ out) {
    long i = ((long)blockIdx.x * 256 + threadIdx.x) * 4;
    float4 f = *(const float4*)(in + i);
    bf16x4 v;
    v[0] = (__bf16)f.x; v[1] = (__bf16)f.y; v[2] = (__bf16)f.z; v[3] = (__bf16)f.w;
    *(bf16x4*)(out + i) = v;
}

__global__ void k_tr(const float* __restrict__ in, __bf16* __restrict__ out, int R, int C) {
    __shared__ float t[32][33];
    int nrt = R >> 5;
    int tr = blockIdx.x % nrt, tc = blockIdx.x / nrt;
    int r0 = tr * 32, c0 = tc * 32;
    int lx = threadIdx.x & 31, ly = threadIdx.x >> 5;
    #pragma unroll
    for (int i = 0; i < 32; i += 8) t[ly + i][lx] = in[(long)(r0 + ly + i) * C + c0 + lx];
    __syncthreads();
    #pragma unroll
    for (int i = 0; i < 32; i += 8) out[(long)(c0 + ly + i) * R + r0 + lx] = (__bf16)t[lx][ly + i];
}

__global__ void k_pack_qkvw(const float* __restrict__ Wq, const float* __restrict__ Wk,
                            const float* __restrict__ Wv, __bf16* __restrict__ out) {
    int bid = blockIdx.x;
    int dht = bid & 1;
    int dt = (bid >> 1) & 31;
    int h = (bid >> 6) & 15;
    int which = bid >> 10;
    const float* W = (which == 0) ? Wq : (which == 1) ? Wk : Wv;
    __shared__ float t[32][33];
    int lx = threadIdx.x & 31, ly = threadIdx.x >> 5;
    const float* src = W + ((long)h * 1024 + dt * 32) * 64 + dht * 32;
    #pragma unroll
    for (int i = 0; i < 32; i += 8) t[ly + i][lx] = src[(ly + i) * 64 + lx];
    __syncthreads();
    __bf16* dst = out + ((long)(which * 1024 + h * 64 + dht * 32)) * 1024 + dt * 32;
    #pragma unroll
    for (int i = 0; i < 32; i += 8) dst[(long)(ly + i) * 1024 + lx] = (__bf16)t[lx][ly + i];
}

__global__ void k_pack_qkvb(const float* bq, const float* bk, const float* bv, float* out) {
    int i = blockIdx.x * 256 + threadIdx.x;
    if (i < 3072) {
        int which = i >> 10, r = i & 1023;
        const float* s = (which == 0) ? bq : (which == 1) ? bk : bv;
        out[i] = s[r];
    }
}

__global__ void k_probe(const unsigned* __restrict__ m, int* flag) {
    __shared__ int bad;
    if (threadIdx.x == 0) bad = 0;
    __syncthreads();
    int local = 0;
    for (int i = 0; i < 64; i++) {
        unsigned w = m[threadIdx.x + 256 * i];
        if (w != 0u && w != 1u && w != 0x3f800000u) local = 1;
    }
    if (local) atomicOr(&bad, 1);
    __syncthreads();
    if (threadIdx.x == 0) *flag = bad ? 0 : 1;
}

__global__ void k_pack_mask(const void* __restrict__ mask, const int* __restrict__ flag,
                            unsigned long long* __restrict__ bits) {
    long wid = ((long)blockIdx.x * 256 + threadIdx.x) >> 6;
    int lane = threadIdx.x & 63;
    long e = wid * 64 + lane;
    bool pred;
    if (*flag) pred = ((const unsigned*)mask)[e] != 0u;
    else       pred = ((const unsigned char*)mask)[e] != 0;
    unsigned long long bal = __ballot(pred);
    if (lane == 0) bits[wid] = bal;
}

// remap mask bits to per-lane words: out[((b*S+s)*16 + kt)*4 + q], bit ct*4+r = mask[s][kt*128+ct*16+q*4+r]
__global__ void k_remap(const unsigned* __restrict__ bitsDW, unsigned* __restrict__ out) {
    int t = blockIdx.x * 256 + threadIdx.x;  // [s:13][kt:4][q:2]
    int q = t & 3, kt = (t >> 2) & 15, srow = t >> 6;
    uint4 md = *(const uint4*)(bitsDW + (long)srow * 64 + kt * 4);
    unsigned d[4] = {md.x, md.y, md.z, md.w};
    unsigned acc = 0;
    #pragma unroll
    for (int ct = 0; ct < 8; ct++) {
        unsigned nib = (d[ct >> 1] >> (((ct & 1) << 4) + q * 4)) & 0xFu;
        acc |= nib << (ct * 4);
    }
    out[t] = acc;
}

// V row-layout [pair][2048][64] -> Vt [pair][64][2048]
__global__ void k_trv(const __bf16* __restrict__ Vrow, __bf16* __restrict__ Vt) {
    __shared__ __bf16 t[32][72];
    int p = blockIdx.x >> 6, ts = blockIdx.x & 63;
    int tid = threadIdx.x;
    const __bf16* src = Vrow + ((long)p * 2048 + ts * 32) * 64;
    int s = tid >> 3, c = (tid & 7) * 8;
    *(bf16x8*)&t[s][c] = *(const bf16x8*)&src[s * 64 + c];
    __syncthreads();
    int dh = tid >> 2, sb = (tid & 3) * 8;
    bf16x8 w;
    #pragma unroll
    for (int j = 0; j < 8; j++) w[j] = t[sb + j][dh];
    *(bf16x8*)&Vt[((long)p * 64 + dh) * 2048 + ts * 32 + sb] = w;
}

// ---------------- GEMM: BK=64, GLDS staging, rotated granules, hoisted read addrs ----------------
#define QSZ 8388608L

template <int MODE>
__global__ __launch_bounds__(256, 4) void k_gemm(const __bf16* __restrict__ A,
                                                 const __bf16* __restrict__ Bt,
                                                 const float* __restrict__ bias,
                                                 void* __restrict__ Cout, int Ndim, int K) {
    __shared__ __align__(16) __bf16 As[128 * 64];
    __shared__ __align__(16) __bf16 Bs[128 * 64];
    const int tid = threadIdx.x;
    const int wave = tid >> 6, lane = tid & 63;
    const int q = lane >> 4, l16 = lane & 15;
    const int wr = wave >> 1, wc = wave & 1;
    const long bm = (long)blockIdx.x * 128;
    const long bn = (long)blockIdx.y * 128;
    floatx4 acc[4][4] = {};

    const int srow = lane >> 3;
    const int scol = (((lane & 7) - srow) & 7) * 8;
    const int r8 = l16 & 7;

    // hoisted LDS read bases (per-iter reads use imm offsets only)
    const char* apA0 = (const char*)As + (wr * 64 + l16) * 128 + ((q + r8) & 7) * 16;
    const char* apA1 = (const char*)As + (wr * 64 + l16) * 128 + ((q + 4 + r8) & 7) * 16;
    const char* apB0 = (const char*)Bs + (wc * 64 + l16) * 128 + ((q + r8) & 7) * 16;
    const char* apB1 = (const char*)Bs + (wc * 64 + l16) * 128 + ((q + 4 + r8) & 7) * 16;

    for (int k0 = 0; k0 < K; k0 += 64) {
        __syncthreads();
        #pragma unroll
        for (int c = 0; c < 4; c++) {
            int row0 = wave * 32 + c * 8;
            GLDS16(&A[(bm + row0 + srow) * K + k0 + scol], (char*)As + row0 * 128);
            GLDS16(&Bt[(bn + row0 + srow) * K + k0 + scol], (char*)Bs + row0 * 128);
        }
        __syncthreads();
        bf16x8 af[4], bfr[4];
        #pragma unroll
        for (int i = 0; i < 4; i++) af[i] = *(const bf16x8*)(apA0 + i * 2048);
        #pragma unroll
        for (int j = 0; j < 4; j++) bfr[j] = *(const bf16x8*)(apB0 + j * 2048);
        #pragma unroll
        for (int i = 0; i < 4; i++)
            #pragma unroll
            for (int j = 0; j < 4; j++)
                acc[i][j] = __builtin_amdgcn_mfma_f32_16x16x32_bf16(af[i], bfr[j], acc[i][j], 0, 0, 0);
        #pragma unroll
        for (int i = 0; i < 4; i++) af[i] = *(const bf16x8*)(apA1 + i * 2048);
        #pragma unroll
        for (int j = 0; j < 4; j++) bfr[j] = *(const bf16x8*)(apB1 + j * 2048);
        #pragma unroll
        for (int i = 0; i < 4; i++)
            #pragma unroll
            for (int j = 0; j < 4; j++)
                acc[i][j] = __builtin_amdgcn_mfma_f32_16x16x32_bf16(af[i], bfr[j], acc[i][j], 0, 0, 0);
    }

    const int mrow0 = (int)bm + wr * 64 + q * 4;
    const int ncol0 = (int)bn + wc * 64;
    #pragma unroll
    for (int j = 0; j < 4; j++) {
        int nbase = ncol0 + j * 16 + l16;
        float bv = bias[nbase];
        #pragma unroll
        for (int i = 0; i < 4; i++) {
            #pragma unroll
            for (int r = 0; r < 4; r++) {
                int mm = mrow0 + i * 16 + r;
                float v = acc[i][j][r] + bv;
                if (MODE == 2) v = fmaxf(v, 0.f);
                if (MODE == 3) {
                    ((float*)Cout)[(long)mm * Ndim + nbase] = v;
                } else if (MODE == 0) {
                    int which = nbase >> 10, rem = nbase & 1023;
                    int hh = rem >> 6, dh = rem & 63;
                    int bb = mm >> 11, ss = mm & 2047;
                    long pr = (long)(bb * 16 + hh);
                    __bf16* o = (__bf16*)Cout;
                    if (which == 0) {
                        v *= 0.03188152837f; // log2(e)/sqrt(2048): softmax in exp2 domain
                        o[(pr * 2048 + ss) * 64 + dh] = (__bf16)v;
                    } else if (which == 1) o[QSZ + (pr * 2048 + ss) * 64 + dh] = (__bf16)v;
                    else o[3 * QSZ + (pr * 2048 + ss) * 64 + dh] = (__bf16)v;
                } else {
                    ((__bf16*)Cout)[(long)mm * Ndim + nbase] = (__bf16)v;
                }
            }
        }
    }
}

// ---------------- flash attention ----------------
// QBLK=128: 4 waves x 32 q-rows (2 q-groups of 16). Each wave's full-Ks/Vts LDS reads
// now serve 2x the q-rows -> per-q LDS read traffic halved vs QBLK=64.
// S^T form; no-max softmax in exp2 domain; per-lane mask word (bit ct*4+r);
// l accumulated by ones-A MFMA alongside PV; all LDS read addrs hoisted; setprio on compute.
__global__ __launch_bounds__(256, 3) void k_attn(const __bf16* __restrict__ Q,
                                                 const __bf16* __restrict__ Kb,
                                                 const __bf16* __restrict__ Vt,
                                                 const unsigned* __restrict__ bitw2,
                                                 __bf16* __restrict__ ctx) {
    __shared__ __align__(16) __bf16 Qs[128 * 64];
    __shared__ __align__(16) __bf16 Ks[128 * 64];
    __shared__ __align__(16) __bf16 Vts[64 * 128];
    const int tid = threadIdx.x, wave = tid >> 6, lane = tid & 63;
    const int q = lane >> 4, l16 = lane & 15;
    const int pair = blockIdx.x & 63, qt = blockIdx.x >> 6;  // qt 0..15
    const int b = pair >> 4, h = pair & 15;

    const int srow8 = lane >> 3;
    const int scol8 = (((lane & 7) - srow8) & 7) * 8;
    const int r8 = l16 & 7;
    const int vrow = lane >> 4;
    const int vl = lane & 15;

    const __bf16* Qp = Q + ((long)pair * SDIM + qt * 128) * 64;
    #pragma unroll
    for (int c = 0; c < 4; c++) {
        int row0 = wave * 32 + c * 8;
        GLDS16(&Qp[(row0 + srow8) * 64 + scol8], (char*)Qs + row0 * 128);
    }
    __syncthreads();
    bf16x8 qf[2][2];
    #pragma unroll
    for (int g = 0; g < 2; g++) {
        const char* qb = (const char*)Qs + (wave * 32 + g * 16 + l16) * 128;
        qf[g][0] = *(const bf16x8*)(qb + ((q + r8) & 7) * 16);
        qf[g][1] = *(const bf16x8*)(qb + ((q + 4 + r8) & 7) * 16);
    }

    // hoisted LDS read bases
    const char* kp0 = (const char*)Ks + l16 * 128 + ((q + r8) & 7) * 16;
    const char* kp1 = (const char*)Ks + l16 * 128 + ((q + 4 + r8) & 7) * 16;
    const char* vp[8];
    #pragma unroll
    for (int ct = 0; ct < 8; ct++)
        vp[ct] = (const char*)Vts + l16 * 256 + (q & 1) * 8 + ((ct * 2 + (q >> 1) + l16) & 15) * 16;
    const int qrow = qt * 128 + wave * 32 + l16;  // q-group 0 row; group 1 = +16
    const unsigned* mp0 = bitw2 + ((long)(b * SDIM + qrow)) * 64 + q;
    const unsigned* mp1 = mp0 + 16 * 64;

    floatx4 o[2][4] = {};
    floatx4 o5[2] = {};
    short4v ones;
    { union { unsigned u[2]; short4v s; } c; c.u[0] = 0x3F803F80u; c.u[1] = 0x3F803F80u; ones = c.s; }

    for (int kt = 0; kt < 16; kt++) {
        __syncthreads();
        const __bf16* Kp = Kb + ((long)pair * SDIM + kt * 128) * 64;
        #pragma unroll
        for (int c = 0; c < 4; c++) {
            int row0 = wave * 32 + c * 8;
            GLDS16(&Kp[(row0 + srow8) * 64 + scol8], (char*)Ks + row0 * 128);
        }
        const __bf16* Vp = Vt + ((long)pair * 64) * SDIM + kt * 128;
        #pragma unroll
        for (int c = 0; c < 4; c++) {
            int row0 = wave * 16 + c * 4;
            int gsrc = ((vl - (c * 4 + vrow)) & 15) * 8;
            GLDS16(&Vp[(long)(row0 + vrow) * SDIM + gsrc], (char*)Vts + row0 * 256);
        }
        const unsigned w32a = mp0[kt * 4];
        const unsigned w32b = mp1[kt * 4];
        __syncthreads();

        __builtin_amdgcn_s_setprio(1);
        // S^T = K·Q^T (exp2 domain), both q-groups share each K fragment read
        floatx4 st0[8], st1[8];
        #pragma unroll
        for (int ct = 0; ct < 8; ct++) {
            bf16x8 kf0 = *(const bf16x8*)(kp0 + ct * 2048);
            bf16x8 kf1 = *(const bf16x8*)(kp1 + ct * 2048);
            floatx4 z0 = {}, z1 = {};
            z0 = __builtin_amdgcn_mfma_f32_16x16x32_bf16(kf0, qf[0][0], z0, 0, 0, 0);
            z1 = __builtin_amdgcn_mfma_f32_16x16x32_bf16(kf0, qf[1][0], z1, 0, 0, 0);
            z0 = __builtin_amdgcn_mfma_f32_16x16x32_bf16(kf1, qf[0][1], z0, 0, 0, 0);
            z1 = __builtin_amdgcn_mfma_f32_16x16x32_bf16(kf1, qf[1][1], z1, 0, 0, 0);
            st0[ct] = z0; st1[ct] = z1;
        }
        // p = exp2(s), mask (constant-literal bit tests), pack via v_perm, PV + ones-MFMA
        // V fragment read once per (ct,d), reused by both q-groups.
        #pragma unroll
        for (int ct = 0; ct < 8; ct++) {
            union { unsigned u[2]; short4v s; } pu0, pu1;
            {
                float p0 = __builtin_amdgcn_exp2f(st0[ct][0]);
                float p1 = __builtin_amdgcn_exp2f(st0[ct][1]);
                float p2 = __builtin_amdgcn_exp2f(st0[ct][2]);
                float p3 = __builtin_amdgcn_exp2f(st0[ct][3]);
                p0 = (w32a & (1u << (ct * 4 + 0))) ? 0.f : p0;
                p1 = (w32a & (1u << (ct * 4 + 1))) ? 0.f : p1;
                p2 = (w32a & (1u << (ct * 4 + 2))) ? 0.f : p2;
                p3 = (w32a & (1u << (ct * 4 + 3))) ? 0.f : p3;
                union { float f; unsigned u; } c0, c1, c2, c3;
                c0.f = p0; c1.f = p1; c2.f = p2; c3.f = p3;
                pu0.u[0] = __builtin_amdgcn_perm(c1.u, c0.u, 0x07060302u);
                pu0.u[1] = __builtin_amdgcn_perm(c3.u, c2.u, 0x07060302u);
            }
            {
                float p0 = __builtin_amdgcn_exp2f(st1[ct][0]);
                float p1 = __builtin_amdgcn_exp2f(st1[ct][1]);
                float p2 = __builtin_amdgcn_exp2f(st1[ct][2]);
                float p3 = __builtin_amdgcn_exp2f(st1[ct][3]);
                p0 = (w32b & (1u << (ct * 4 + 0))) ? 0.f : p0;
                p1 = (w32b & (1u << (ct * 4 + 1))) ? 0.f : p1;
                p2 = (w32b & (1u << (ct * 4 + 2))) ? 0.f : p2;
                p3 = (w32b & (1u << (ct * 4 + 3))) ? 0.f : p3;
                union { float f; unsigned u; } c0, c1, c2, c3;
                c0.f = p0; c1.f = p1; c2.f = p2; c3.f = p3;
                pu1.u[0] = __builtin_amdgcn_perm(c1.u, c0.u, 0x07060302u);
                pu1.u[1] = __builtin_amdgcn_perm(c3.u, c2.u, 0x07060302u);
            }
            #pragma unroll
            for (int d = 0; d < 4; d++) {
                union { bf16x4 b; short4v s; } vu;
                vu.b = *(const bf16x4*)(vp[ct] + d * 4096);
                o[0][d] = __builtin_amdgcn_mfma_f32_16x16x16bf16_1k(vu.s, pu0.s, o[0][d], 0, 0, 0);
                o[1][d] = __builtin_amdgcn_mfma_f32_16x16x16bf16_1k(vu.s, pu1.s, o[1][d], 0, 0, 0);
            }
            o5[0] = __builtin_amdgcn_mfma_f32_16x16x16bf16_1k(ones, pu0.s, o5[0], 0, 0, 0);
            o5[1] = __builtin_amdgcn_mfma_f32_16x16x16bf16_1k(ones, pu1.s, o5[1], 0, 0, 0);
        }
        __builtin_amdgcn_s_setprio(0);
    }
    #pragma unroll
    for (int g = 0; g < 2; g++) {
        float inv = 1.0f / o5[g][0];
        long base = ((long)b * SDIM + qrow + g * 16) * DDIM + h * 64;
        #pragma unroll
        for (int d = 0; d < 4; d++) {
            bf16x4 w;
            #pragma unroll
            for (int r = 0; r < 4; r++) w[r] = (__bf16)(o[g][d][r] * inv);
            *(bf16x4*)&ctx[base + d * 16 + q * 4] = w;
        }
    }
}

// ---------------- launch ----------------

extern "C" void kernel_launch(void* const* d_in, const int* in_sizes, int n_in,
                              void* d_out, int out_size, void* d_ws, size_t ws_size,
                              hipStream_t stream) {
    const float* x = (const float*)d_in[0];
    const void* mask = d_in[1];
    const float* Wq = (const float*)d_in[2];
    const float* bq = (const float*)d_in[3];
    const float* Wk = (const float*)d_in[4];
    const float* bk = (const float*)d_in[5];
    const float* Wv = (const float*)d_in[6];
    const float* bv = (const float*)d_in[7];
    const float* Wo = (const float*)d_in[8];
    const float* bo = (const float*)d_in[9];
    const float* W1 = (const float*)d_in[10];
    const float* b1 = (const float*)d_in[11];
    const float* W2 = (const float*)d_in[12];
    const float* b2 = (const float*)d_in[13];

    char* ws = (char*)d_ws;
    __bf16* xb   = (__bf16*)(ws + 0);          // 16 MB; aliased as ctx after GEMM0
    __bf16* Qb   = (__bf16*)(ws + 16777216);   // 16 MB; aliased as attn_out after attention
    __bf16* Kb   = (__bf16*)(ws + 33554432);   // 16 MB (= Qb + QSZ)
    __bf16* Vtb  = (__bf16*)(ws + 50331648);   // 16 MB (= Qb + 2*QSZ)
    __bf16* Vrow = (__bf16*)(ws + 67108864);   // 16 MB (= Qb + 3*QSZ); dead after k_trv
    __bf16* hbuf = (__bf16*)(ws + 33554432);   // 64 MB (aliases Kb/Vtb/Vrow after attention)
    __bf16* wqkvt = (__bf16*)(ws + 100663296); // 6 MB (bits/bits2 alias after GEMM0)
    __bf16* wot  = (__bf16*)(ws + 106954752);  // 2 MB
    __bf16* w1t  = (__bf16*)(ws + 109051904);  // 8 MB
    __bf16* w2t  = (__bf16*)(ws + 117440512);  // 8 MB
    float* bqkv  = (float*)(ws + 125829120);   // 12 KB
    int* flag    = (int*)(ws + 125841408);     // 4 B
    __bf16* ctx = xb;
    __bf16* attn_out = Qb;
    unsigned long long* bits = (unsigned long long*)wqkvt;           // 2 MB
    unsigned* bits2 = (unsigned*)((char*)wqkvt + 2097152);           // 2 MB
    (void)Vrow;

    k_f2b<<<8192, 256, 0, stream>>>(x, xb);
    k_pack_qkvw<<<3072, 256, 0, stream>>>(Wq, Wk, Wv, wqkvt);
    k_pack_qkvb<<<12, 256, 0, stream>>>(bq, bk, bv, bqkv);
    k_tr<<<1024, 256, 0, stream>>>(Wo, wot, 1024, 1024);
    k_tr<<<4096, 256, 0, stream>>>(W1, w1t, 1024, 4096);
    k_tr<<<4096, 256, 0, stream>>>(W2, w2t, 4096, 1024);
    k_probe<<<1, 256, 0, stream>>>((const unsigned*)mask, flag);

    {   // QKV projection: [8192,1024] x [3072,1024]^T; V written coalesced to Vrow
        dim3 g(64, 24);
        k_gemm<0><<<g, 256, 0, stream>>>(xb, wqkvt, bqkv, (void*)Qb, 3072, 1024);
    }
    k_trv<<<4096, 256, 0, stream>>>(Vrow, Vtb);
    k_pack_mask<<<65536, 256, 0, stream>>>(mask, flag, bits);
    k_remap<<<2048, 256, 0, stream>>>((const unsigned*)bits, bits2);
    k_attn<<<1024, 256, 0, stream>>>(Qb, Kb, Vtb, bits2, ctx);
    {   // output projection
        dim3 g(64, 8);
        k_gemm<1><<<g, 256, 0, stream>>>(ctx, wot, bo, (void*)attn_out, 1024, 1024);
    }
    {   // FFN1 + relu
        dim3 g(64, 32);
        k_gemm<2><<<g, 256, 0, stream>>>(attn_out, w1t, b1, (void*)hbuf, 4096, 1024);
    }
    {   // FFN2 -> fp32 out
        dim3 g(64, 8);
        k_gemm<3><<<g, 256, 0, stream>>>(hbuf, w2t, b2, d_out, 1024, 4096);
    }
}

// Round 2
// 582.933 us; speedup vs baseline: 1.0339x; 1.0219x over previous
//
#include <hip/hip_runtime.h>
#include <hip/hip_bf16.h>

// EncoderLayer: B=4,S=2048,D=1024,H=16,DH=64,DFF=4096
// prep -> GEMM0 qkv (Q pre-scaled by log2e/sqrt(S)) -> k_trv -> mask bits -> remap
//   -> flash-attn (QBLK=128, K/V double-buffered in LDS, counted vmcnt pipeline:
//      stage(t+1) -> s_waitcnt vmcnt(10)+s_barrier -> compute(t) -> s_barrier)
//   -> GEMM1 -> GEMM2 -> GEMM3

#define SDIM 2048
#define DDIM 1024

using floatx4 = __attribute__((ext_vector_type(4))) float;
using bf16x8  = __attribute__((ext_vector_type(8))) __bf16;
using bf16x4  = __attribute__((ext_vector_type(4))) __bf16;
using short4v = __attribute__((ext_vector_type(4))) short;

#define GLDS16(gptr, lptr)                                                        \
    __builtin_amdgcn_global_load_lds(                                             \
        (const __attribute__((address_space(1))) void*)(uintptr_t)(gptr),         \
        (__attribute__((address_space(3))) void*)(uintptr_t)(lptr), 16, 0, 0)

// ---------------- prep kernels ----------------

__global__ void k_f2b(const float* __restrict__ in, __bf16* __restrict__ out) {
    long i = ((long)blockIdx.x * 256 + threadIdx.x) * 4;
    float4 f = *(const float4*)(in + i);
    bf16x4 v;
    v[0] = (__bf16)f.x; v[1] = (__bf16)f.y; v[2] = (__bf16)f.z; v[3] = (__bf16)f.w;
    *(bf16x4*)(out + i) = v;
}

__global__ void k_tr(const float* __restrict__ in, __bf16* __restrict__ out, int R, int C) {
    __shared__ float t[32][33];
    int nrt = R >> 5;
    int tr = blockIdx.x % nrt, tc = blockIdx.x / nrt;
    int r0 = tr * 32, c0 = tc * 32;
    int lx = threadIdx.x & 31, ly = threadIdx.x >> 5;
    #pragma unroll
    for (int i = 0; i < 32; i += 8) t[ly + i][lx] = in[(long)(r0 + ly + i) * C + c0 + lx];
    __syncthreads();
    #pragma unroll
    for (int i = 0; i < 32; i += 8) out[(long)(c0 + ly + i) * R + r0 + lx] = (__bf16)t[lx][ly + i];
}

__global__ void k_pack_qkvw(const float* __restrict__ Wq, const float* __restrict__ Wk,
                            const float* __restrict__ Wv, __bf16* __restrict__ out) {
    int bid = blockIdx.x;
    int dht = bid & 1;
    int dt = (bid >> 1) & 31;
    int h = (bid >> 6) & 15;
    int which = bid >> 10;
    const float* W = (which == 0) ? Wq : (which == 1) ? Wk : Wv;
    __shared__ float t[32][33];
    int lx = threadIdx.x & 31, ly = threadIdx.x >> 5;
    const float* src = W + ((long)h * 1024 + dt * 32) * 64 + dht * 32;
    #pragma unroll
    for (int i = 0; i < 32; i += 8) t[ly + i][lx] = src[(ly + i) * 64 + lx];
    __syncthreads();
    __bf16* dst = out + ((long)(which * 1024 + h * 64 + dht * 32)) * 1024 + dt * 32;
    #pragma unroll
    for (int i = 0; i < 32; i += 8) dst[(long)(ly + i) * 1024 + lx] = (__bf16)t[lx][ly + i];
}

__global__ void k_pack_qkvb(const float* bq, const float* bk, const float* bv, float* out) {
    int i = blockIdx.x * 256 + threadIdx.x;
    if (i < 3072) {
        int which = i >> 10, r = i & 1023;
        const float* s = (which == 0) ? bq : (which == 1) ? bk : bv;
        out[i] = s[r];
    }
}

__global__ void k_probe(const unsigned* __restrict__ m, int* flag) {
    __shared__ int bad;
    if (threadIdx.x == 0) bad = 0;
    __syncthreads();
    int local = 0;
    for (int i = 0; i < 64; i++) {
        unsigned w = m[threadIdx.x + 256 * i];
        if (w != 0u && w != 1u && w != 0x3f800000u) local = 1;
    }
    if (local) atomicOr(&bad, 1);
    __syncthreads();
    if (threadIdx.x == 0) *flag = bad ? 0 : 1;
}

__global__ void k_pack_mask(const void* __restrict__ mask, const int* __restrict__ flag,
                            unsigned long long* __restrict__ bits) {
    long wid = ((long)blockIdx.x * 256 + threadIdx.x) >> 6;
    int lane = threadIdx.x & 63;
    long e = wid * 64 + lane;
    bool pred;
    if (*flag) pred = ((const unsigned*)mask)[e] != 0u;
    else       pred = ((const unsigned char*)mask)[e] != 0;
    unsigned long long bal = __ballot(pred);
    if (lane == 0) bits[wid] = bal;
}

// remap mask bits to per-lane words: out[((b*S+s)*16 + q)*16 + kt], bit ct*4+r = mask[s][kt*128+ct*16+q*4+r]
// layout [s][q][kt] so k_attn's per-tile word is mp[kt] (contiguous in kt)
__global__ void k_remap(const unsigned* __restrict__ bitsDW, unsigned* __restrict__ out) {
    int t = blockIdx.x * 256 + threadIdx.x;  // [s:13][kt:4][q:2]
    int q = t & 3, kt = (t >> 2) & 15, srow = t >> 6;
    uint4 md = *(const uint4*)(bitsDW + (long)srow * 64 + kt * 4);
    unsigned d[4] = {md.x, md.y, md.z, md.w};
    unsigned acc = 0;
    #pragma unroll
    for (int ct = 0; ct < 8; ct++) {
        unsigned nib = (d[ct >> 1] >> (((ct & 1) << 4) + q * 4)) & 0xFu;
        acc |= nib << (ct * 4);
    }
    out[srow * 64 + q * 16 + kt] = acc;
}

// V row-layout [pair][2048][64] -> Vt [pair][64][2048]
__global__ void k_trv(const __bf16* __restrict__ Vrow, __bf16* __restrict__ Vt) {
    __shared__ __bf16 t[32][72];
    int p = blockIdx.x >> 6, ts = blockIdx.x & 63;
    int tid = threadIdx.x;
    const __bf16* src = Vrow + ((long)p * 2048 + ts * 32) * 64;
    int s = tid >> 3, c = (tid & 7) * 8;
    *(bf16x8*)&t[s][c] = *(const bf16x8*)&src[s * 64 + c];
    __syncthreads();
    int dh = tid >> 2, sb = (tid & 3) * 8;
    bf16x8 w;
    #pragma unroll
    for (int j = 0; j < 8; j++) w[j] = t[sb + j][dh];
    *(bf16x8*)&Vt[((long)p * 64 + dh) * 2048 + ts * 32 + sb] = w;
}

// ---------------- GEMM: BK=64, GLDS staging, rotated granules, hoisted read addrs ----------------
#define QSZ 8388608L

template <int MODE>
__global__ __launch_bounds__(256, 4) void k_gemm(const __bf16* __restrict__ A,
                                                 const __bf16* __restrict__ Bt,
                                                 const float* __restrict__ bias,
                                                 void* __restrict__ Cout, int Ndim, int K) {
    __shared__ __align__(16) __bf16 As[128 * 64];
    __shared__ __align__(16) __bf16 Bs[128 * 64];
    const int tid = threadIdx.x;
    const int wave = tid >> 6, lane = tid & 63;
    const int q = lane >> 4, l16 = lane & 15;
    const int wr = wave >> 1, wc = wave & 1;
    const long bm = (long)blockIdx.x * 128;
    const long bn = (long)blockIdx.y * 128;
    floatx4 acc[4][4] = {};

    const int srow = lane >> 3;
    const int scol = (((lane & 7) - srow) & 7) * 8;
    const int r8 = l16 & 7;

    // hoisted LDS read bases (per-iter reads use imm offsets only)
    const char* apA0 = (const char*)As + (wr * 64 + l16) * 128 + ((q + r8) & 7) * 16;
    const char* apA1 = (const char*)As + (wr * 64 + l16) * 128 + ((q + 4 + r8) & 7) * 16;
    const char* apB0 = (const char*)Bs + (wc * 64 + l16) * 128 + ((q + r8) & 7) * 16;
    const char* apB1 = (const char*)Bs + (wc * 64 + l16) * 128 + ((q + 4 + r8) & 7) * 16;

    for (int k0 = 0; k0 < K; k0 += 64) {
        __syncthreads();
        #pragma unroll
        for (int c = 0; c < 4; c++) {
            int row0 = wave * 32 + c * 8;
            GLDS16(&A[(bm + row0 + srow) * K + k0 + scol], (char*)As + row0 * 128);
            GLDS16(&Bt[(bn + row0 + srow) * K + k0 + scol], (char*)Bs + row0 * 128);
        }
        __syncthreads();
        bf16x8 af[4], bfr[4];
        #pragma unroll
        for (int i = 0; i < 4; i++) af[i] = *(const bf16x8*)(apA0 + i * 2048);
        #pragma unroll
        for (int j = 0; j < 4; j++) bfr[j] = *(const bf16x8*)(apB0 + j * 2048);
        #pragma unroll
        for (int i = 0; i < 4; i++)
            #pragma unroll
            for (int j = 0; j < 4; j++)
                acc[i][j] = __builtin_amdgcn_mfma_f32_16x16x32_bf16(af[i], bfr[j], acc[i][j], 0, 0, 0);
        #pragma unroll
        for (int i = 0; i < 4; i++) af[i] = *(const bf16x8*)(apA1 + i * 2048);
        #pragma unroll
        for (int j = 0; j < 4; j++) bfr[j] = *(const bf16x8*)(apB1 + j * 2048);
        #pragma unroll
        for (int i = 0; i < 4; i++)
            #pragma unroll
            for (int j = 0; j < 4; j++)
                acc[i][j] = __builtin_amdgcn_mfma_f32_16x16x32_bf16(af[i], bfr[j], acc[i][j], 0, 0, 0);
    }

    const int mrow0 = (int)bm + wr * 64 + q * 4;
    const int ncol0 = (int)bn + wc * 64;
    #pragma unroll
    for (int j = 0; j < 4; j++) {
        int nbase = ncol0 + j * 16 + l16;
        float bv = bias[nbase];
        #pragma unroll
        for (int i = 0; i < 4; i++) {
            #pragma unroll
            for (int r = 0; r < 4; r++) {
                int mm = mrow0 + i * 16 + r;
                float v = acc[i][j][r] + bv;
                if (MODE == 2) v = fmaxf(v, 0.f);
                if (MODE == 3) {
                    ((float*)Cout)[(long)mm * Ndim + nbase] = v;
                } else if (MODE == 0) {
                    int which = nbase >> 10, rem = nbase & 1023;
                    int hh = rem >> 6, dh = rem & 63;
                    int bb = mm >> 11, ss = mm & 2047;
                    long pr = (long)(bb * 16 + hh);
                    __bf16* o = (__bf16*)Cout;
                    if (which == 0) {
                        v *= 0.03188152837f; // log2(e)/sqrt(2048): softmax in exp2 domain
                        o[(pr * 2048 + ss) * 64 + dh] = (__bf16)v;
                    } else if (which == 1) o[QSZ + (pr * 2048 + ss) * 64 + dh] = (__bf16)v;
                    else o[3 * QSZ + (pr * 2048 + ss) * 64 + dh] = (__bf16)v;
                } else {
                    ((__bf16*)Cout)[(long)mm * Ndim + nbase] = (__bf16)v;
                }
            }
        }
    }
}

// ---------------- flash attention ----------------
// QBLK=128: 4 waves x 32 q-rows (2 q-groups of 16).
// K/V double-buffered (80KB LDS, 2 blocks/CU). Counted-vmcnt pipeline: each phase
// issues next tile's 2 mask loads + 8 GLDS, then "s_waitcnt vmcnt(10); s_barrier"
// waits only on the PREVIOUS phase's batch -> stage latency hides under compute.
// Raw s_barrier after compute releases the buffer for overwrite.
__global__ __launch_bounds__(256, 2) void k_attn(const __bf16* __restrict__ Q,
                                                 const __bf16* __restrict__ Kb,
                                                 const __bf16* __restrict__ Vt,
                                                 const unsigned* __restrict__ bitw2,
                                                 __bf16* __restrict__ ctx) {
    __shared__ __align__(16) __bf16 Qs[128 * 64];
    __shared__ __align__(16) __bf16 Ks[2][128 * 64];
    __shared__ __align__(16) __bf16 Vts[2][64 * 128];
    const int tid = threadIdx.x, wave = tid >> 6, lane = tid & 63;
    const int q = lane >> 4, l16 = lane & 15;
    const int pair = blockIdx.x & 63, qt = blockIdx.x >> 6;  // qt 0..15
    const int b = pair >> 4, h = pair & 15;

    const int srow8 = lane >> 3;
    const int scol8 = (((lane & 7) - srow8) & 7) * 8;
    const int r8 = l16 & 7;
    const int vrow = lane >> 4;
    const int vl = lane & 15;

    // hoisted LDS read bases (buffer 1 = +16384 bytes, folded as imm offset)
    const char* kp0 = (const char*)Ks + l16 * 128 + ((q + r8) & 7) * 16;
    const char* kp1 = (const char*)Ks + l16 * 128 + ((q + 4 + r8) & 7) * 16;
    const char* vp[8];
    #pragma unroll
    for (int ct = 0; ct < 8; ct++)
        vp[ct] = (const char*)Vts + l16 * 256 + (q & 1) * 8 + ((ct * 2 + (q >> 1) + l16) & 15) * 16;
    const int qrow = qt * 128 + wave * 32 + l16;  // q-group 0 row; group 1 = +16
    const unsigned* mp0 = bitw2 + ((long)(b * SDIM + qrow)) * 64 + q * 16;  // [s][q][kt]
    const unsigned* mp1 = mp0 + 16 * 64;

    floatx4 o[2][4] = {};
    floatx4 o5[2] = {};
    short4v ones;
    { union { unsigned u[2]; short4v s; } c; c.u[0] = 0x3F803F80u; c.u[1] = 0x3F803F80u; ones = c.s; }

    auto stage_kv = [&](int kt, int bufsel) __attribute__((always_inline)) {
        const __bf16* Kp = Kb + ((long)pair * SDIM + kt * 128) * 64;
        #pragma unroll
        for (int c = 0; c < 4; c++) {
            int row0 = wave * 32 + c * 8;
            GLDS16(&Kp[(row0 + srow8) * 64 + scol8], (char*)Ks + bufsel * 16384 + row0 * 128);
        }
        const __bf16* Vp = Vt + ((long)pair * 64) * SDIM + kt * 128;
        #pragma unroll
        for (int c = 0; c < 4; c++) {
            int row0 = wave * 16 + c * 4;
            int gsrc = ((vl - (c * 4 + vrow)) & 15) * 8;
            GLDS16(&Vp[(long)(row0 + vrow) * SDIM + gsrc], (char*)Vts + bufsel * 16384 + row0 * 256);
        }
    };

    // prologue: Q -> LDS, masks(0), K/V tile0 -> buf0
    const __bf16* Qp = Q + ((long)pair * SDIM + qt * 128) * 64;
    #pragma unroll
    for (int c = 0; c < 4; c++) {
        int row0 = wave * 32 + c * 8;
        GLDS16(&Qp[(row0 + srow8) * 64 + scol8], (char*)Qs + row0 * 128);
    }
    unsigned waA = mp0[0], wbA = mp1[0];
    stage_kv(0, 0);
    // drain Q (4 loads) + mask loads; leave tile0's 8 GLDS in flight
    asm volatile("s_waitcnt vmcnt(8)\n\ts_barrier" ::: "memory");

    bf16x8 qf[2][2];
    #pragma unroll
    for (int g = 0; g < 2; g++) {
        const char* qb = (const char*)Qs + (wave * 32 + g * 16 + l16) * 128;
        qf[g][0] = *(const bf16x8*)(qb + ((q + r8) & 7) * 16);
        qf[g][1] = *(const bf16x8*)(qb + ((q + 4 + r8) & 7) * 16);
    }

    auto compute = [&](int off, unsigned w32a, unsigned w32b) __attribute__((always_inline)) {
        __builtin_amdgcn_s_setprio(1);
        // S^T = K·Q^T (exp2 domain), both q-groups share each K fragment read
        floatx4 st0[8], st1[8];
        #pragma unroll
        for (int ct = 0; ct < 8; ct++) {
            bf16x8 kf0 = *(const bf16x8*)(kp0 + off + ct * 2048);
            bf16x8 kf1 = *(const bf16x8*)(kp1 + off + ct * 2048);
            floatx4 z0 = {}, z1 = {};
            z0 = __builtin_amdgcn_mfma_f32_16x16x32_bf16(kf0, qf[0][0], z0, 0, 0, 0);
            z1 = __builtin_amdgcn_mfma_f32_16x16x32_bf16(kf0, qf[1][0], z1, 0, 0, 0);
            z0 = __builtin_amdgcn_mfma_f32_16x16x32_bf16(kf1, qf[0][1], z0, 0, 0, 0);
            z1 = __builtin_amdgcn_mfma_f32_16x16x32_bf16(kf1, qf[1][1], z1, 0, 0, 0);
            st0[ct] = z0; st1[ct] = z1;
        }
        // p = exp2(s), mask, pack via v_perm, PV + ones-MFMA (V frag read shared by groups)
        #pragma unroll
        for (int ct = 0; ct < 8; ct++) {
            union { unsigned u[2]; short4v s; } pu0, pu1;
            {
                float p0 = __builtin_amdgcn_exp2f(st0[ct][0]);
                float p1 = __builtin_amdgcn_exp2f(st0[ct][1]);
                float p2 = __builtin_amdgcn_exp2f(st0[ct][2]);
                float p3 = __builtin_amdgcn_exp2f(st0[ct][3]);
                p0 = (w32a & (1u << (ct * 4 + 0))) ? 0.f : p0;
                p1 = (w32a & (1u << (ct * 4 + 1))) ? 0.f : p1;
                p2 = (w32a & (1u << (ct * 4 + 2))) ? 0.f : p2;
                p3 = (w32a & (1u << (ct * 4 + 3))) ? 0.f : p3;
                union { float f; unsigned u; } c0, c1, c2, c3;
                c0.f = p0; c1.f = p1; c2.f = p2; c3.f = p3;
                pu0.u[0] = __builtin_amdgcn_perm(c1.u, c0.u, 0x07060302u);
                pu0.u[1] = __builtin_amdgcn_perm(c3.u, c2.u, 0x07060302u);
            }
            {
                float p0 = __builtin_amdgcn_exp2f(st1[ct][0]);
                float p1 = __builtin_amdgcn_exp2f(st1[ct][1]);
                float p2 = __builtin_amdgcn_exp2f(st1[ct][2]);
                float p3 = __builtin_amdgcn_exp2f(st1[ct][3]);
                p0 = (w32b & (1u << (ct * 4 + 0))) ? 0.f : p0;
                p1 = (w32b & (1u << (ct * 4 + 1))) ? 0.f : p1;
                p2 = (w32b & (1u << (ct * 4 + 2))) ? 0.f : p2;
                p3 = (w32b & (1u << (ct * 4 + 3))) ? 0.f : p3;
                union { float f; unsigned u; } c0, c1, c2, c3;
                c0.f = p0; c1.f = p1; c2.f = p2; c3.f = p3;
                pu1.u[0] = __builtin_amdgcn_perm(c1.u, c0.u, 0x07060302u);
                pu1.u[1] = __builtin_amdgcn_perm(c3.u, c2.u, 0x07060302u);
            }
            #pragma unroll
            for (int d = 0; d < 4; d++) {
                union { bf16x4 b; short4v s; } vu;
                vu.b = *(const bf16x4*)(vp[ct] + off + d * 4096);
                o[0][d] = __builtin_amdgcn_mfma_f32_16x16x16bf16_1k(vu.s, pu0.s, o[0][d], 0, 0, 0);
                o[1][d] = __builtin_amdgcn_mfma_f32_16x16x16bf16_1k(vu.s, pu1.s, o[1][d], 0, 0, 0);
            }
            o5[0] = __builtin_amdgcn_mfma_f32_16x16x16bf16_1k(ones, pu0.s, o5[0], 0, 0, 0);
            o5[1] = __builtin_amdgcn_mfma_f32_16x16x16bf16_1k(ones, pu1.s, o5[1], 0, 0, 0);
        }
        __builtin_amdgcn_s_setprio(0);
    };

    // main pipeline: 7 double-iterations + tail (tiles 14,15)
    #pragma unroll 1
    for (int kt = 0; kt < 14; kt += 2) {
        unsigned waB = mp0[kt + 1], wbB = mp1[kt + 1];
        stage_kv(kt + 1, 1);
        asm volatile("s_waitcnt vmcnt(10)\n\ts_barrier" ::: "memory");
        compute(0, waA, wbA);
        asm volatile("s_barrier" ::: "memory");
        waA = mp0[kt + 2]; wbA = mp1[kt + 2];
        stage_kv(kt + 2, 0);
        asm volatile("s_waitcnt vmcnt(10)\n\ts_barrier" ::: "memory");
        compute(16384, waB, wbB);
        asm volatile("s_barrier" ::: "memory");
    }
    {
        unsigned waB = mp0[15], wbB = mp1[15];
        stage_kv(15, 1);
        asm volatile("s_waitcnt vmcnt(10)\n\ts_barrier" ::: "memory");
        compute(0, waA, wbA);
        asm volatile("s_barrier" ::: "memory");
        asm volatile("s_waitcnt vmcnt(0)\n\ts_barrier" ::: "memory");
        compute(16384, waB, wbB);
    }

    #pragma unroll
    for (int g = 0; g < 2; g++) {
        float inv = 1.0f / o5[g][0];
        long base = ((long)b * SDIM + qrow + g * 16) * DDIM + h * 64;
        #pragma unroll
        for (int d = 0; d < 4; d++) {
            bf16x4 w;
            #pragma unroll
            for (int r = 0; r < 4; r++) w[r] = (__bf16)(o[g][d][r] * inv);
            *(bf16x4*)&ctx[base + d * 16 + q * 4] = w;
        }
    }
}

// ---------------- launch ----------------

extern "C" void kernel_launch(void* const* d_in, const int* in_sizes, int n_in,
                              void* d_out, int out_size, void* d_ws, size_t ws_size,
                              hipStream_t stream) {
    const float* x = (const float*)d_in[0];
    const void* mask = d_in[1];
    const float* Wq = (const float*)d_in[2];
    const float* bq = (const float*)d_in[3];
    const float* Wk = (const float*)d_in[4];
    const float* bk = (const float*)d_in[5];
    const float* Wv = (const float*)d_in[6];
    const float* bv = (const float*)d_in[7];
    const float* Wo = (const float*)d_in[8];
    const float* bo = (const float*)d_in[9];
    const float* W1 = (const float*)d_in[10];
    const float* b1 = (const float*)d_in[11];
    const float* W2 = (const float*)d_in[12];
    const float* b2 = (const float*)d_in[13];

    char* ws = (char*)d_ws;
    __bf16* xb   = (__bf16*)(ws + 0);          // 16 MB; aliased as ctx after GEMM0
    __bf16* Qb   = (__bf16*)(ws + 16777216);   // 16 MB; aliased as attn_out after attention
    __bf16* Kb   = (__bf16*)(ws + 33554432);   // 16 MB (= Qb + QSZ)
    __bf16* Vtb  = (__bf16*)(ws + 50331648);   // 16 MB (= Qb + 2*QSZ)
    __bf16* Vrow = (__bf16*)(ws + 67108864);   // 16 MB (= Qb + 3*QSZ); dead after k_trv
    __bf16* hbuf = (__bf16*)(ws + 33554432);   // 64 MB (aliases Kb/Vtb/Vrow after attention)
    __bf16* wqkvt = (__bf16*)(ws + 100663296); // 6 MB (bits/bits2 alias after GEMM0)
    __bf16* wot  = (__bf16*)(ws + 106954752);  // 2 MB
    __bf16* w1t  = (__bf16*)(ws + 109051904);  // 8 MB
    __bf16* w2t  = (__bf16*)(ws + 117440512);  // 8 MB
    float* bqkv  = (float*)(ws + 125829120);   // 12 KB
    int* flag    = (int*)(ws + 125841408);     // 4 B
    __bf16* ctx = xb;
    __bf16* attn_out = Qb;
    unsigned long long* bits = (unsigned long long*)wqkvt;           // 2 MB
    unsigned* bits2 = (unsigned*)((char*)wqkvt + 2097152);           // 2 MB
    (void)Vrow;

    k_f2b<<<8192, 256, 0, stream>>>(x, xb);
    k_pack_qkvw<<<3072, 256, 0, stream>>>(Wq, Wk, Wv, wqkvt);
    k_pack_qkvb<<<12, 256, 0, stream>>>(bq, bk, bv, bqkv);
    k_tr<<<1024, 256, 0, stream>>>(Wo, wot, 1024, 1024);
    k_tr<<<4096, 256, 0, stream>>>(W1, w1t, 1024, 4096);
    k_tr<<<4096, 256, 0, stream>>>(W2, w2t, 4096, 1024);
    k_probe<<<1, 256, 0, stream>>>((const unsigned*)mask, flag);

    {   // QKV projection: [8192,1024] x [3072,1024]^T; V written coalesced to Vrow
        dim3 g(64, 24);
        k_gemm<0><<<g, 256, 0, stream>>>(xb, wqkvt, bqkv, (void*)Qb, 3072, 1024);
    }
    k_trv<<<4096, 256, 0, stream>>>(Vrow, Vtb);
    k_pack_mask<<<65536, 256, 0, stream>>>(mask, flag, bits);
    k_remap<<<2048, 256, 0, stream>>>((const unsigned*)bits, bits2);
    k_attn<<<1024, 256, 0, stream>>>(Qb, Kb, Vtb, bits2, ctx);
    {   // output projection
        dim3 g(64, 8);
        k_gemm<1><<<g, 256, 0, stream>>>(ctx, wot, bo, (void*)attn_out, 1024, 1024);
    }
    {   // FFN1 + relu
        dim3 g(64, 32);
        k_gemm<2><<<g, 256, 0, stream>>>(attn_out, w1t, b1, (void*)hbuf, 4096, 1024);
    }
    {   // FFN2 -> fp32 out
        dim3 g(64, 8);
        k_gemm<3><<<g, 256, 0, stream>>>(hbuf, w2t, b2, d_out, 1024, 4096);
    }
}